// Round 1
// baseline (497.926 us; speedup 1.0000x reference)
//
#include <hip/hip_runtime.h>
#include <cstdint>

#define Bq 4
#define Lq 4096
#define Hq 256
#define NHq 8
#define Tq 64
#define WINq 16
#define Dq 32
#define NSLOTS 33      // 2*WIN+1
#define NEG_SLOPE 5.0f
#define MASK_FILL -1e12f
#define RPB 8

__device__ __forceinline__ float leaky(float x) { return x >= 0.f ? x : NEG_SLOPE * x; }

// ---------------- types projection + down_t ----------------
__global__ void k_types(const float* __restrict__ types, const float* __restrict__ Wt,
                        const float* __restrict__ bt, const float* __restrict__ down,
                        float* __restrict__ types_h, float* __restrict__ down_t) {
    int row = blockIdx.x;          // b*T + t
    int h = threadIdx.x;           // 0..255
    __shared__ float in[Hq];
    __shared__ float outr[Hq];
    in[h] = types[(size_t)row * Hq + h];
    __syncthreads();
    float acc = bt[h];
    for (int k = 0; k < Hq; ++k) acc += in[k] * Wt[k * Hq + h];
    types_h[(size_t)row * Hq + h] = acc;
    outr[h] = acc;
    __syncthreads();
    if (h < NHq) {
        int b = row / Tq, t = row % Tq;
        float s = 0.f;
        for (int d = 0; d < Dq; ++d) s += outr[h * Dq + d] * down[h * Dq + d];
        down_t[(b * NHq + h) * Tq + t] = s;
    }
}

// ---------------- context projection + upon_q / down_s ----------------
__global__ void k_ctx(const float* __restrict__ ctx, const float* __restrict__ Wc,
                      const float* __restrict__ bc, const float* __restrict__ upon,
                      const float* __restrict__ down,
                      float* __restrict__ ctx_h, float* __restrict__ uq,
                      float* __restrict__ dsv) {
    int row0 = blockIdx.x * RPB;   // rows are b*L + l, 8 consecutive share b
    int h = threadIdx.x;
    __shared__ float in[RPB][Hq];
    for (int r = 0; r < RPB; ++r) in[r][h] = ctx[(size_t)(row0 + r) * Hq + h];
    __syncthreads();
    float acc[RPB];
    float bv = bc[h];
#pragma unroll
    for (int r = 0; r < RPB; ++r) acc[r] = bv;
    for (int k = 0; k < Hq; ++k) {
        float w = Wc[k * Hq + h];
#pragma unroll
        for (int r = 0; r < RPB; ++r) acc[r] += in[r][k] * w;
    }
    __syncthreads();               // reuse `in` for projected rows
#pragma unroll
    for (int r = 0; r < RPB; ++r) {
        ctx_h[(size_t)(row0 + r) * Hq + h] = acc[r];
        in[r][h] = acc[r];
    }
    __syncthreads();
    if (h < 64) {
        int r = h >> 3, n = h & 7;
        float su = 0.f, sd = 0.f;
        for (int d = 0; d < Dq; ++d) {
            float v = in[r][n * Dq + d];
            su += v * upon[n * Dq + d];
            sd += v * down[n * Dq + d];
        }
        int row = row0 + r;
        int b = row / Lq, l = row % Lq;
        uq[(b * NHq + n) * Lq + l] = su;
        dsv[(b * NHq + n) * Lq + l] = sd;
    }
}

// ---------------- attention (logits + softmax + update) ----------------
__global__ void k_attn(const float* __restrict__ ctx_h, const float* __restrict__ types_h,
                       const float* __restrict__ cross, const float* __restrict__ uq,
                       const float* __restrict__ dsv, const float* __restrict__ dt,
                       const unsigned char* __restrict__ maskp,
                       float* __restrict__ update) {
    int row = blockIdx.x;          // b*L + l
    int b = row >> 12, l = row & (Lq - 1);
    int tid = threadIdx.x, n = tid >> 5, i = tid & 31;
    // mask encoding: bool8 (byte[1]==1 since row 0 all-true) vs int32 (byte[1]==0)
    bool mask_b8 = (maskp[1] != 0);

    __shared__ float ch[Hq];
    __shared__ float cr[Hq];
    __shared__ float w[NHq][104];   // 97 logits->weights, padded

    ch[tid] = ctx_h[(size_t)row * Hq + tid];
    __syncthreads();
    // cross_h[n][i] = sum_d ch[n][d] * cross[n][d][i]
    {
        const float* crn = cross + n * (Dq * Dq);
        float a = 0.f;
#pragma unroll
        for (int d = 0; d < Dq; ++d) a += ch[n * Dq + d] * crn[d * Dq + i];
        cr[tid] = a;
    }
    __syncthreads();
    const float* crh = &cr[n * Dq];
    float uq_l = uq[(b * NHq + n) * Lq + l];

    // ---- type logits: t = i, i+32 ----
    float s_t[2];
#pragma unroll
    for (int q = 0; q < 2; ++q) {
        int t = i + 32 * q;
        const float* th = types_h + ((size_t)(b * Tq + t) * NHq + n) * Dq;
        float dot = 0.f;
#pragma unroll
        for (int d = 0; d < Dq; ++d) dot += crh[d] * th[d];
        s_t[q] = leaky(uq_l + dt[(b * NHq + n) * Tq + t] + dot);
    }

    // ---- window logits: v = i (and v=32 on lane 0) ----
    float s_c[2] = {MASK_FILL, MASK_FILL};
    int nv = (i == 0) ? 2 : 1;
    for (int q = 0; q < nv; ++q) {
        int v = i + 32 * q;
        int ou = (v < 17) ? 0 : v - 16;
        int od = (v < 16) ? v - 16 : 0;
        int ju = l + ou, jd = l + od;
        bool valid = (jd >= 0) && (ju < Lq);
        int jum = (ju >= Lq) ? ju - Lq : ju;
        int jdm = (jd < 0) ? jd + Lq : jd;
        bool m = valid;
        if (m) {
            unsigned char mb = mask_b8 ? maskp[b * Lq + jum]
                                       : maskp[(size_t)(b * Lq + jum) * 4];
            m = (mb != 0);
        }
        if (m) {
            const float* chj = ctx_h + (size_t)(b * Lq + jum) * Hq + n * Dq;
            float dot = 0.f;
#pragma unroll
            for (int d = 0; d < Dq; ++d) dot += crh[d] * chj[d];
            float s = uq[(b * NHq + n) * Lq + jum] + dsv[(b * NHq + n) * Lq + jdm] + dot;
            s_c[q] = leaky(s);
        }
    }

    // ---- softmax over 97 (register + 32-lane shfl) ----
    float m = fmaxf(fmaxf(s_t[0], s_t[1]), fmaxf(s_c[0], s_c[1]));
#pragma unroll
    for (int k = 16; k >= 1; k >>= 1) m = fmaxf(m, __shfl_xor(m, k, 32));
    float p_t0 = __expf(s_t[0] - m);
    float p_t1 = __expf(s_t[1] - m);
    float p_c0 = (s_c[0] > -1e11f) ? __expf(s_c[0] - m) : 0.f;
    float p_c1 = (s_c[1] > -1e11f) ? __expf(s_c[1] - m) : 0.f;
    float sum = p_t0 + p_t1 + p_c0 + p_c1;
#pragma unroll
    for (int k = 16; k >= 1; k >>= 1) sum += __shfl_xor(sum, k, 32);
    float inv = 1.f / sum;
    w[n][i] = p_t0 * inv;
    w[n][i + 32] = p_t1 * inv;
    w[n][64 + i] = p_c0 * inv;
    if (i == 0) w[n][96] = p_c1 * inv;
    __syncthreads();

    // ---- weighted update: d = i ----
    float acc = 0.f;
    for (int t = 0; t < Tq; ++t)
        acc += w[n][t] * types_h[((size_t)(b * Tq + t) * NHq + n) * Dq + i];
    // v = 0..16 all gather position l (value = ch in LDS)
    float wself = 0.f;
#pragma unroll
    for (int v = 0; v < 17; ++v) wself += w[n][64 + v];
    acc += wself * ch[tid];
#pragma unroll
    for (int v = 17; v < NSLOTS; ++v) {
        int ju = l + v - 16;
        int jum = (ju >= Lq) ? ju - Lq : ju;
        acc += w[n][64 + v] * ctx_h[(size_t)(b * Lq + jum) * Hq + n * Dq + i];
    }
    update[(size_t)row * Hq + tid] = acc;
}

// ---------------- output GEMM + tanh ----------------
__global__ void k_out(const float* __restrict__ update, const float* __restrict__ ctx,
                      const float* __restrict__ Wo, const float* __restrict__ bo,
                      float* __restrict__ out) {
    int row0 = blockIdx.x * RPB;
    int h = threadIdx.x;
    __shared__ float in[RPB][Hq];
    for (int r = 0; r < RPB; ++r) {
        size_t idx = (size_t)(row0 + r) * Hq + h;
        in[r][h] = update[idx] + ctx[idx];
    }
    __syncthreads();
    float acc[RPB];
    float bv = bo[h];
#pragma unroll
    for (int r = 0; r < RPB; ++r) acc[r] = bv;
    for (int k = 0; k < Hq; ++k) {
        float wv = Wo[k * Hq + h];
#pragma unroll
        for (int r = 0; r < RPB; ++r) acc[r] += in[r][k] * wv;
    }
#pragma unroll
    for (int r = 0; r < RPB; ++r)
        out[(size_t)(row0 + r) * Hq + h] = tanhf(acc[r]);
}

extern "C" void kernel_launch(void* const* d_in, const int* in_sizes, int n_in,
                              void* d_out, int out_size, void* d_ws, size_t ws_size,
                              hipStream_t stream) {
    const float* context   = (const float*)d_in[0];
    const float* types     = (const float*)d_in[1];
    const unsigned char* cmask = (const unsigned char*)d_in[2];
    const float* W_types   = (const float*)d_in[3];
    const float* b_types   = (const float*)d_in[4];
    const float* W_context = (const float*)d_in[5];
    const float* b_context = (const float*)d_in[6];
    const float* upon      = (const float*)d_in[7];
    const float* down      = (const float*)d_in[8];
    const float* cross     = (const float*)d_in[9];
    const float* W_out     = (const float*)d_in[10];
    const float* b_out     = (const float*)d_in[11];
    float* out = (float*)d_out;
    float* ws  = (float*)d_ws;

    float* types_h = ws;                    // 65536
    float* down_t  = ws + 65536;            // 2048
    float* uqp     = ws + 67584;            // 131072
    float* dsvp    = ws + 198656;           // 131072
    float* ctx_h   = ws + 329728;           // 4194304
    float* update  = ws + 4524032;          // 4194304  (total ~34.9 MB)

    k_types<<<Bq * Tq, Hq, 0, stream>>>(types, W_types, b_types, down, types_h, down_t);
    k_ctx<<<Bq * Lq / RPB, Hq, 0, stream>>>(context, W_context, b_context, upon, down,
                                            ctx_h, uqp, dsvp);
    k_attn<<<Bq * Lq, Hq, 0, stream>>>(ctx_h, types_h, cross, uqp, dsvp, down_t,
                                       cmask, update);
    k_out<<<Bq * Lq / RPB, Hq, 0, stream>>>(update, context, W_out, b_out, out);
}

// Round 2
// 397.325 us; speedup vs baseline: 1.2532x; 1.2532x over previous
//
#include <hip/hip_runtime.h>
#include <cstdint>

#define Bq 4
#define Lq 4096
#define Hq 256
#define NHq 8
#define Tq 64
#define WINq 16
#define Dq 32
#define NSLOTS 33      // 2*WIN+1
#define NEG_SLOPE 5.0f
#define MASK_FILL -1e12f
#define RPB 16

__device__ __forceinline__ float leaky(float x) { return x >= 0.f ? x : NEG_SLOPE * x; }

__device__ __forceinline__ float4 fma4(float4 a, float s, float4 c) {
    float4 r;
    r.x = fmaf(a.x, s, c.x); r.y = fmaf(a.y, s, c.y);
    r.z = fmaf(a.z, s, c.z); r.w = fmaf(a.w, s, c.w);
    return r;
}
__device__ __forceinline__ float dot4(float4 a, float4 b) {
    return a.x * b.x + a.y * b.y + a.z * b.z + a.w * b.w;
}

// ---------------- types projection + down_t ----------------
__global__ void k_types(const float* __restrict__ types, const float* __restrict__ Wt,
                        const float* __restrict__ bt, const float* __restrict__ down,
                        float* __restrict__ types_h, float* __restrict__ down_t) {
    int row = blockIdx.x;          // b*T + t
    int h = threadIdx.x;           // 0..255
    __shared__ float in[Hq];
    __shared__ float outr[Hq];
    in[h] = types[(size_t)row * Hq + h];
    __syncthreads();
    float acc = bt[h];
    for (int k = 0; k < Hq; ++k) acc += in[k] * Wt[k * Hq + h];
    types_h[(size_t)row * Hq + h] = acc;
    outr[h] = acc;
    __syncthreads();
    if (h < NHq) {
        int b = row / Tq, t = row % Tq;
        float s = 0.f;
        for (int d = 0; d < Dq; ++d) s += outr[h * Dq + d] * down[h * Dq + d];
        down_t[(b * NHq + h) * Tq + t] = s;
    }
}

// ---------------- context projection + upon_q / down_s ----------------
__global__ void __launch_bounds__(256) k_ctx(
        const float* __restrict__ ctx, const float* __restrict__ Wc,
        const float* __restrict__ bc, const float* __restrict__ upon,
        const float* __restrict__ down,
        float* __restrict__ ctx_h, float* __restrict__ uq,
        float* __restrict__ dsv) {
    int row0 = blockIdx.x * RPB;   // rows are b*L + l; all RPB rows share b
    int tid = threadIdx.x;
    __shared__ float in[RPB][Hq];
    {
        const float4* src = (const float4*)(ctx + (size_t)row0 * Hq);
        float4* dst = (float4*)(&in[0][0]);
#pragma unroll
        for (int j = 0; j < (RPB * Hq / 4) / 256; ++j)
            dst[tid + j * 256] = src[tid + j * 256];
    }
    __syncthreads();
    int c = tid & 63;              // float4 column group: cols 4c..4c+3
    int rs = (tid >> 6) << 2;      // rows rs..rs+3
    float4 bv = ((const float4*)bc)[c];
    float4 acc0 = bv, acc1 = bv, acc2 = bv, acc3 = bv;
    for (int k = 0; k < Hq; ++k) {
        float4 wv = ((const float4*)(Wc + (size_t)k * Hq))[c];
        acc0 = fma4(wv, in[rs + 0][k], acc0);
        acc1 = fma4(wv, in[rs + 1][k], acc1);
        acc2 = fma4(wv, in[rs + 2][k], acc2);
        acc3 = fma4(wv, in[rs + 3][k], acc3);
    }
    ((float4*)(ctx_h + (size_t)(row0 + rs + 0) * Hq))[c] = acc0;
    ((float4*)(ctx_h + (size_t)(row0 + rs + 1) * Hq))[c] = acc1;
    ((float4*)(ctx_h + (size_t)(row0 + rs + 2) * Hq))[c] = acc2;
    ((float4*)(ctx_h + (size_t)(row0 + rs + 3) * Hq))[c] = acc3;
    __syncthreads();               // all reads of `in` done; reuse for projected
    ((float4*)&in[rs + 0][0])[c] = acc0;
    ((float4*)&in[rs + 1][0])[c] = acc1;
    ((float4*)&in[rs + 2][0])[c] = acc2;
    ((float4*)&in[rs + 3][0])[c] = acc3;
    __syncthreads();
    if (tid < RPB * NHq) {
        int r = tid >> 3, n = tid & 7;
        float su = 0.f, sd = 0.f;
        for (int d = 0; d < Dq; ++d) {
            float v = in[r][n * Dq + d];
            su += v * upon[n * Dq + d];
            sd += v * down[n * Dq + d];
        }
        int b = row0 >> 12, l = (row0 & (Lq - 1)) + r;
        uq[(b * NHq + n) * Lq + l] = su;
        dsv[(b * NHq + n) * Lq + l] = sd;
    }
}

// ---------------- attention (logits + softmax + update) ----------------
__global__ void __launch_bounds__(256) k_attn(
        const float* __restrict__ ctx_h, const float* __restrict__ types_h,
        const float* __restrict__ cross, const float* __restrict__ uq,
        const float* __restrict__ dsv, const float* __restrict__ dt,
        const unsigned char* __restrict__ maskp,
        float* __restrict__ update) {
    int row = blockIdx.x;          // b*L + l
    int b = row >> 12, l = row & (Lq - 1);
    int tid = threadIdx.x, n = tid >> 5, i = tid & 31;
    bool mask_b8 = (maskp[1] != 0);   // bool8 vs int32 probe (row 0 all-true)

    __shared__ float ch[Hq];
    __shared__ float cr[Hq];
    __shared__ float w[NHq][104];

    ch[tid] = ctx_h[(size_t)row * Hq + tid];
    __syncthreads();
    {   // cross_h[n][i] = sum_d ch[n][d] * cross[n][d][i]   (coalesced in i)
        const float* crn = cross + n * (Dq * Dq);
        const float* chn = &ch[n * Dq];
        float a = 0.f;
#pragma unroll
        for (int d = 0; d < Dq; ++d) a = fmaf(chn[d], crn[d * Dq + i], a);
        cr[tid] = a;
    }
    __syncthreads();

    // keep crh in registers as 8 float4
    float4 crv[8];
    {
        const float4* crh4 = (const float4*)&cr[n * Dq];
#pragma unroll
        for (int j = 0; j < 8; ++j) crv[j] = crh4[j];
    }
    float uq_l = uq[(b * NHq + n) * Lq + l];

    // ---- type logits: t = i, i+32 (float4 row dots) ----
    float s_t[2];
#pragma unroll
    for (int q = 0; q < 2; ++q) {
        int t = i + 32 * q;
        const float4* th4 = (const float4*)(types_h + (size_t)(b * Tq + t) * Hq + n * Dq);
        float dot = 0.f;
#pragma unroll
        for (int j = 0; j < 8; ++j) dot += dot4(crv[j], th4[j]);
        s_t[q] = leaky(uq_l + dt[(b * NHq + n) * Tq + t] + dot);
    }

    // ---- window logits: v = i (and v=32 on lane 0) ----
    float s_c[2] = {MASK_FILL, MASK_FILL};
    int nv = (i == 0) ? 2 : 1;
    for (int q = 0; q < nv; ++q) {
        int v = i + 32 * q;
        int ou = (v < 17) ? 0 : v - 16;
        int od = (v < 16) ? v - 16 : 0;
        int ju = l + ou, jd = l + od;
        bool valid = (jd >= 0) && (ju < Lq);
        int jum = (ju >= Lq) ? ju - Lq : ju;
        int jdm = (jd < 0) ? jd + Lq : jd;
        bool m = valid;
        if (m) {
            unsigned char mb = mask_b8 ? maskp[b * Lq + jum]
                                       : maskp[(size_t)(b * Lq + jum) * 4];
            m = (mb != 0);
        }
        if (m) {
            const float4* chj4 = (const float4*)(ctx_h + (size_t)(b * Lq + jum) * Hq + n * Dq);
            float dot = 0.f;
#pragma unroll
            for (int j = 0; j < 8; ++j) dot += dot4(crv[j], chj4[j]);
            float s = uq[(b * NHq + n) * Lq + jum] + dsv[(b * NHq + n) * Lq + jdm] + dot;
            s_c[q] = leaky(s);
        }
    }

    // ---- softmax over 97 (registers + 32-lane shfl) ----
    float m = fmaxf(fmaxf(s_t[0], s_t[1]), fmaxf(s_c[0], s_c[1]));
#pragma unroll
    for (int k = 16; k >= 1; k >>= 1) m = fmaxf(m, __shfl_xor(m, k, 32));
    float p_t0 = __expf(s_t[0] - m);
    float p_t1 = __expf(s_t[1] - m);
    float p_c0 = (s_c[0] > -1e11f) ? __expf(s_c[0] - m) : 0.f;
    float p_c1 = (s_c[1] > -1e11f) ? __expf(s_c[1] - m) : 0.f;
    float sum = p_t0 + p_t1 + p_c0 + p_c1;
#pragma unroll
    for (int k = 16; k >= 1; k >>= 1) sum += __shfl_xor(sum, k, 32);
    float inv = 1.f / sum;
    w[n][i] = p_t0 * inv;
    w[n][i + 32] = p_t1 * inv;
    w[n][64 + i] = p_c0 * inv;
    if (i == 0) w[n][96] = p_c1 * inv;
    __syncthreads();

    // ---- weighted update: d = i (coalesced) ----
    float acc = 0.f;
    for (int t = 0; t < Tq; ++t)
        acc = fmaf(w[n][t], types_h[(size_t)(b * Tq + t) * Hq + n * Dq + i], acc);
    float wself = 0.f;
#pragma unroll
    for (int v = 0; v < 17; ++v) wself += w[n][64 + v];
    acc = fmaf(wself, ch[tid], acc);
#pragma unroll
    for (int v = 17; v < NSLOTS; ++v) {
        int ju = l + v - 16;
        int jum = (ju >= Lq) ? ju - Lq : ju;
        acc = fmaf(w[n][64 + v], ctx_h[(size_t)(b * Lq + jum) * Hq + n * Dq + i], acc);
    }
    update[(size_t)row * Hq + tid] = acc;
}

// ---------------- output GEMM + tanh ----------------
__global__ void __launch_bounds__(256) k_out(
        const float* __restrict__ update, const float* __restrict__ ctx,
        const float* __restrict__ Wo, const float* __restrict__ bo,
        float* __restrict__ out) {
    int row0 = blockIdx.x * RPB;
    int tid = threadIdx.x;
    __shared__ float in[RPB][Hq];
    {
        const float4* s0 = (const float4*)(update + (size_t)row0 * Hq);
        const float4* s1 = (const float4*)(ctx + (size_t)row0 * Hq);
        float4* dst = (float4*)(&in[0][0]);
#pragma unroll
        for (int j = 0; j < (RPB * Hq / 4) / 256; ++j) {
            float4 a = s0[tid + j * 256], bvv = s1[tid + j * 256];
            float4 r; r.x = a.x + bvv.x; r.y = a.y + bvv.y; r.z = a.z + bvv.z; r.w = a.w + bvv.w;
            dst[tid + j * 256] = r;
        }
    }
    __syncthreads();
    int c = tid & 63;
    int rs = (tid >> 6) << 2;
    float4 bv = ((const float4*)bo)[c];
    float4 acc0 = bv, acc1 = bv, acc2 = bv, acc3 = bv;
    for (int k = 0; k < Hq; ++k) {
        float4 wv = ((const float4*)(Wo + (size_t)k * Hq))[c];
        acc0 = fma4(wv, in[rs + 0][k], acc0);
        acc1 = fma4(wv, in[rs + 1][k], acc1);
        acc2 = fma4(wv, in[rs + 2][k], acc2);
        acc3 = fma4(wv, in[rs + 3][k], acc3);
    }
    float4 o;
#define STORE_ROW(J, A) \
    o.x = tanhf(A.x); o.y = tanhf(A.y); o.z = tanhf(A.z); o.w = tanhf(A.w); \
    ((float4*)(out + (size_t)(row0 + rs + J) * Hq))[c] = o;
    STORE_ROW(0, acc0) STORE_ROW(1, acc1) STORE_ROW(2, acc2) STORE_ROW(3, acc3)
#undef STORE_ROW
}

extern "C" void kernel_launch(void* const* d_in, const int* in_sizes, int n_in,
                              void* d_out, int out_size, void* d_ws, size_t ws_size,
                              hipStream_t stream) {
    const float* context   = (const float*)d_in[0];
    const float* types     = (const float*)d_in[1];
    const unsigned char* cmask = (const unsigned char*)d_in[2];
    const float* W_types   = (const float*)d_in[3];
    const float* b_types   = (const float*)d_in[4];
    const float* W_context = (const float*)d_in[5];
    const float* b_context = (const float*)d_in[6];
    const float* upon      = (const float*)d_in[7];
    const float* down      = (const float*)d_in[8];
    const float* cross     = (const float*)d_in[9];
    const float* W_out     = (const float*)d_in[10];
    const float* b_out     = (const float*)d_in[11];
    float* out = (float*)d_out;
    float* ws  = (float*)d_ws;

    float* types_h = ws;                    // 65536
    float* down_t  = ws + 65536;            // 2048
    float* uqp     = ws + 67584;            // 131072
    float* dsvp    = ws + 198656;           // 131072
    float* ctx_h   = ws + 329728;           // 4194304
    float* update  = ws + 4524032;          // 4194304

    k_types<<<Bq * Tq, Hq, 0, stream>>>(types, W_types, b_types, down, types_h, down_t);
    k_ctx<<<Bq * Lq / RPB, 256, 0, stream>>>(context, W_context, b_context, upon, down,
                                             ctx_h, uqp, dsvp);
    k_attn<<<Bq * Lq, Hq, 0, stream>>>(ctx_h, types_h, cross, uqp, dsvp, down_t,
                                       cmask, update);
    k_out<<<Bq * Lq / RPB, 256, 0, stream>>>(update, context, W_out, b_out, out);
}

// Round 4
// 373.948 us; speedup vs baseline: 1.3315x; 1.0625x over previous
//
#include <hip/hip_runtime.h>
#include <cstdint>

#define Bq 4
#define Lq 4096
#define Hq 256
#define NHq 8
#define Tq 64
#define WINq 16
#define Dq 32
#define NSLOTS 33      // 2*WIN+1
#define NEG_SLOPE 5.0f
#define MASK_FILL -1e12f
#define RPB 32         // rows per block for the two dense GEMMs

__device__ __forceinline__ float leaky(float x) { return x >= 0.f ? x : NEG_SLOPE * x; }

__device__ __forceinline__ float4 fma4(float4 a, float s, float4 c) {
    float4 r;
    r.x = fmaf(a.x, s, c.x); r.y = fmaf(a.y, s, c.y);
    r.z = fmaf(a.z, s, c.z); r.w = fmaf(a.w, s, c.w);
    return r;
}

// ---------------- types projection + down_t + transposed copy ----------------
__global__ void k_types(const float* __restrict__ types, const float* __restrict__ Wt,
                        const float* __restrict__ bt, const float* __restrict__ down,
                        float* __restrict__ types_h, float* __restrict__ types_hT,
                        float* __restrict__ down_t) {
    int row = blockIdx.x;          // b*T + t
    int h = threadIdx.x;           // 0..255  (= n*32+d)
    int b = row >> 6, t = row & 63;
    __shared__ float in[Hq];
    __shared__ float outr[Hq];
    in[h] = types[(size_t)row * Hq + h];
    __syncthreads();
    float acc = bt[h];
    for (int k = 0; k < Hq; k += 4) {
        float4 iv = *(const float4*)&in[k];
        acc = fmaf(iv.x, Wt[(k + 0) * Hq + h], acc);
        acc = fmaf(iv.y, Wt[(k + 1) * Hq + h], acc);
        acc = fmaf(iv.z, Wt[(k + 2) * Hq + h], acc);
        acc = fmaf(iv.w, Wt[(k + 3) * Hq + h], acc);
    }
    types_h[(size_t)row * Hq + h] = acc;
    types_hT[(size_t)(b * Hq + h) * Tq + t] = acc;   // [b][n][d][t]
    outr[h] = acc;
    __syncthreads();
    if (h < NHq) {
        float s = 0.f;
        for (int d = 0; d < Dq; ++d) s += outr[h * Dq + d] * down[h * Dq + d];
        down_t[(b * NHq + h) * Tq + t] = s;
    }
}

// ---------------- context projection -> ctx_hT + upon_q / down_s ----------------
__global__ void __launch_bounds__(256) k_ctx(
        const float* __restrict__ ctx, const float* __restrict__ Wc,
        const float* __restrict__ bc, const float* __restrict__ upon,
        const float* __restrict__ down,
        float* __restrict__ ctx_hT, float* __restrict__ uq,
        float* __restrict__ dsv) {
    int row0 = blockIdx.x * RPB;   // rows b*L + l; all RPB rows share b
    int b = row0 >> 12, l0 = row0 & (Lq - 1);
    int tid = threadIdx.x;
    __shared__ float in[RPB][Hq];
    {
        const float4* src = (const float4*)(ctx + (size_t)row0 * Hq);
        float4* dst = (float4*)(&in[0][0]);
#pragma unroll
        for (int j = 0; j < (RPB * Hq / 4) / 256; ++j)
            dst[tid + j * 256] = src[tid + j * 256];
    }
    __syncthreads();
    int c = tid & 63;              // float4 column group
    int rs = (tid >> 6) * 8;       // 8 rows per thread (wave-uniform rs)
    const float4* W4 = (const float4*)Wc;
    float4 bv = ((const float4*)bc)[c];
    float4 acc[8];
#pragma unroll
    for (int j = 0; j < 8; ++j) acc[j] = bv;
    for (int k = 0; k < Hq; k += 4) {
        float4 w0 = W4[(k + 0) * 64 + c];
        float4 w1 = W4[(k + 1) * 64 + c];
        float4 w2 = W4[(k + 2) * 64 + c];
        float4 w3 = W4[(k + 3) * 64 + c];
#pragma unroll
        for (int j = 0; j < 8; ++j) {
            float4 iv = *(const float4*)&in[rs + j][k];
            acc[j] = fma4(w0, iv.x, acc[j]);
            acc[j] = fma4(w1, iv.y, acc[j]);
            acc[j] = fma4(w2, iv.z, acc[j]);
            acc[j] = fma4(w3, iv.w, acc[j]);
        }
    }
    __syncthreads();               // raw `in` no longer needed
#pragma unroll
    for (int j = 0; j < 8; ++j)
        ((float4*)&in[rs + j][0])[c] = acc[j];
    __syncthreads();
    // uq / dsv : thread -> (r, n)
    {
        int r = tid >> 3, n = tid & 7;
        float su = 0.f, sd = 0.f;
        for (int d = 0; d < Dq; ++d) {
            float v = in[r][n * Dq + d];
            su += v * upon[n * Dq + d];
            sd += v * down[n * Dq + d];
        }
        uq[(b * NHq + n) * Lq + l0 + r] = su;
        dsv[(b * NHq + n) * Lq + l0 + r] = sd;
    }
    // transposed store: thread tid owns channel (n*32+d)=tid, writes 32 l's
    {
        float* dst = ctx_hT + (size_t)(b * Hq + tid) * Lq + l0;
#pragma unroll
        for (int j = 0; j < 8; ++j) {
            float4 o;
            o.x = in[4 * j + 0][tid];
            o.y = in[4 * j + 1][tid];
            o.z = in[4 * j + 2][tid];
            o.w = in[4 * j + 3][tid];
            ((float4*)dst)[j] = o;
        }
    }
}

// ---------------- attention (logits + softmax + update) ----------------
__global__ void __launch_bounds__(256) k_attn(
        const float* __restrict__ ctx_hT, const float* __restrict__ types_h,
        const float* __restrict__ types_hT, const float* __restrict__ cross,
        const float* __restrict__ uq, const float* __restrict__ dsv,
        const float* __restrict__ dt, const unsigned char* __restrict__ maskp,
        float* __restrict__ update) {
    int row = blockIdx.x;          // b*L + l
    int b = row >> 12, l = row & (Lq - 1);
    int tid = threadIdx.x, n = tid >> 5, i = tid & 31;
    bool mask_b8 = (maskp[1] != 0);   // bool8 vs int32 probe (row 0 all-true)

    __shared__ float ch[Hq];
    __shared__ float cr[Hq];
    __shared__ float vals[NHq][Dq][NSLOTS];
    __shared__ float w[NHq][104];

    const float* Tb = ctx_hT + (size_t)b * Hq * Lq;
    ch[tid] = Tb[(size_t)tid * Lq + l];     // tid = n*32+d (one divergent load)
    __syncthreads();
    {   // cr[n][i] = sum_d ch[n][d] * cross[n][d][i]   (coalesced in i)
        const float* crn = cross + n * (Dq * Dq);
        const float* chn = &ch[n * Dq];
        float a = 0.f;
#pragma unroll
        for (int d = 0; d < Dq; ++d) a = fmaf(chn[d], crn[d * Dq + i], a);
        cr[tid] = a;
    }
    __syncthreads();
    const float* crh = &cr[n * Dq];
    float uq_l = uq[(b * NHq + n) * Lq + l];

    // ---- type logits: t = i, i+32 (coalesced via types_hT) ----
    float s_t0 = 0.f, s_t1 = 0.f;
    {
        const float* Ttyp = types_hT + (size_t)(b * NHq + n) * Dq * Tq;  // [d][t]
#pragma unroll
        for (int d = 0; d < Dq; ++d) {
            float cv = crh[d];
            s_t0 = fmaf(cv, Ttyp[d * Tq + i], s_t0);
            s_t1 = fmaf(cv, Ttyp[d * Tq + i + 32], s_t1);
        }
    }
    s_t0 = leaky(uq_l + dt[(b * NHq + n) * Tq + i] + s_t0);
    s_t1 = leaky(uq_l + dt[(b * NHq + n) * Tq + i + 32] + s_t1);

    // ---- window logits: v = i (coalesced via ctx_hT), stash values in LDS ----
    const float* Tn = Tb + (size_t)n * Dq * Lq;
    float s_c0, s_c1 = MASK_FILL;
    {
        int v = i;
        int ou = (v < 17) ? 0 : v - 16;
        int od = (v < 16) ? v - 16 : 0;
        int ju = l + ou, jd = l + od;
        bool valid = (jd >= 0) && (ju < Lq);
        int jum = (ju >= Lq) ? ju - Lq : ju;
        int jdm = (jd < 0) ? jd + Lq : jd;
        float dot = 0.f;
#pragma unroll
        for (int d = 0; d < Dq; ++d) {
            float val = Tn[(size_t)d * Lq + jum];
            vals[n][d][v] = val;
            dot = fmaf(crh[d], val, dot);
        }
        bool m = valid;
        if (m) {
            unsigned char mb = mask_b8 ? maskp[b * Lq + jum]
                                       : maskp[(size_t)(b * Lq + jum) * 4];
            m = (mb != 0);
        }
        s_c0 = m ? leaky(uq[(b * NHq + n) * Lq + jum] +
                         dsv[(b * NHq + n) * Lq + jdm] + dot)
                 : MASK_FILL;
    }
    if (i == 0) {   // v = 32: ou=16, od=0
        int ju = l + 16;
        int jum = (ju >= Lq) ? ju - Lq : ju;
        bool valid = (ju < Lq);
        float dot = 0.f;
#pragma unroll
        for (int d = 0; d < Dq; ++d) {
            float val = Tn[(size_t)d * Lq + jum];
            vals[n][d][32] = val;
            dot = fmaf(crh[d], val, dot);
        }
        bool m = valid;
        if (m) {
            unsigned char mb = mask_b8 ? maskp[b * Lq + jum]
                                       : maskp[(size_t)(b * Lq + jum) * 4];
            m = (mb != 0);
        }
        s_c1 = m ? leaky(uq[(b * NHq + n) * Lq + jum] +
                         dsv[(b * NHq + n) * Lq + l] + dot)
                 : MASK_FILL;
    }

    // ---- softmax over 97 (registers + 32-lane shfl) ----
    float m = fmaxf(fmaxf(s_t0, s_t1), fmaxf(s_c0, s_c1));
#pragma unroll
    for (int k = 16; k >= 1; k >>= 1) m = fmaxf(m, __shfl_xor(m, k, 32));
    float p_t0 = __expf(s_t0 - m);
    float p_t1 = __expf(s_t1 - m);
    float p_c0 = (s_c0 > -1e11f) ? __expf(s_c0 - m) : 0.f;
    float p_c1 = (s_c1 > -1e11f) ? __expf(s_c1 - m) : 0.f;
    float sum = p_t0 + p_t1 + p_c0 + p_c1;
#pragma unroll
    for (int k = 16; k >= 1; k >>= 1) sum += __shfl_xor(sum, k, 32);
    float inv = 1.f / sum;
    w[n][i] = p_t0 * inv;
    w[n][i + 32] = p_t1 * inv;
    w[n][64 + i] = p_c0 * inv;
    if (i == 0) w[n][96] = p_c1 * inv;
    __syncthreads();

    // ---- weighted update: d = i ----
    float acc = 0.f;
    {   // type part: coalesced row-major types_h reads (L1-resident)
        const float* th = types_h + (size_t)(b * Tq) * Hq + n * Dq + i;
        for (int t = 0; t < Tq; ++t)
            acc = fmaf(w[n][t], th[(size_t)t * Hq], acc);
    }
    {   // window part: from LDS stash, banks (i+v)&31 — conflict-free
#pragma unroll
        for (int v = 0; v < NSLOTS; ++v)
            acc = fmaf(w[n][64 + v], vals[n][i][v], acc);
    }
    update[(size_t)row * Hq + tid] = acc;
}

// ---------------- output GEMM + tanh ----------------
__global__ void __launch_bounds__(256) k_out(
        const float* __restrict__ update, const float* __restrict__ ctx,
        const float* __restrict__ Wo, const float* __restrict__ bo,
        float* __restrict__ out) {
    int row0 = blockIdx.x * RPB;
    int tid = threadIdx.x;
    __shared__ float in[RPB][Hq];
    {
        const float4* s0 = (const float4*)(update + (size_t)row0 * Hq);
        const float4* s1 = (const float4*)(ctx + (size_t)row0 * Hq);
        float4* dst = (float4*)(&in[0][0]);
#pragma unroll
        for (int j = 0; j < (RPB * Hq / 4) / 256; ++j) {
            float4 a = s0[tid + j * 256], bvv = s1[tid + j * 256];
            float4 r; r.x = a.x + bvv.x; r.y = a.y + bvv.y;
            r.z = a.z + bvv.z; r.w = a.w + bvv.w;
            dst[tid + j * 256] = r;
        }
    }
    __syncthreads();
    int c = tid & 63;
    int rs = (tid >> 6) * 8;
    const float4* W4 = (const float4*)Wo;
    float4 bv = ((const float4*)bo)[c];
    float4 acc[8];
#pragma unroll
    for (int j = 0; j < 8; ++j) acc[j] = bv;
    for (int k = 0; k < Hq; k += 4) {
        float4 w0 = W4[(k + 0) * 64 + c];
        float4 w1 = W4[(k + 1) * 64 + c];
        float4 w2 = W4[(k + 2) * 64 + c];
        float4 w3 = W4[(k + 3) * 64 + c];
#pragma unroll
        for (int j = 0; j < 8; ++j) {
            float4 iv = *(const float4*)&in[rs + j][k];
            acc[j] = fma4(w0, iv.x, acc[j]);
            acc[j] = fma4(w1, iv.y, acc[j]);
            acc[j] = fma4(w2, iv.z, acc[j]);
            acc[j] = fma4(w3, iv.w, acc[j]);
        }
    }
#pragma unroll
    for (int j = 0; j < 8; ++j) {
        float4 o;
        o.x = tanhf(acc[j].x); o.y = tanhf(acc[j].y);
        o.z = tanhf(acc[j].z); o.w = tanhf(acc[j].w);
        ((float4*)(out + (size_t)(row0 + rs + j) * Hq))[c] = o;
    }
}

extern "C" void kernel_launch(void* const* d_in, const int* in_sizes, int n_in,
                              void* d_out, int out_size, void* d_ws, size_t ws_size,
                              hipStream_t stream) {
    const float* context   = (const float*)d_in[0];
    const float* types     = (const float*)d_in[1];
    const unsigned char* cmask = (const unsigned char*)d_in[2];
    const float* W_types   = (const float*)d_in[3];
    const float* b_types   = (const float*)d_in[4];
    const float* W_context = (const float*)d_in[5];
    const float* b_context = (const float*)d_in[6];
    const float* upon      = (const float*)d_in[7];
    const float* down      = (const float*)d_in[8];
    const float* cross     = (const float*)d_in[9];
    const float* W_out     = (const float*)d_in[10];
    const float* b_out     = (const float*)d_in[11];
    float* out = (float*)d_out;
    float* ws  = (float*)d_ws;

    // ws holds ONLY the two big 16MB tensors (32 MiB total — proven-safe size).
    float* ctx_hT   = ws;             // 4194304  [b][n][d][l]
    float* update   = ws + 4194304;   // 4194304

    // Small intermediates live in d_out scratch: produced by k_types/k_ctx,
    // consumed by k_attn, then k_out overwrites every element of d_out with
    // the final result (stream-ordered, so safe).
    float* types_h  = out;            // 65536   [b][t][h]
    float* types_hT = out + 65536;    // 65536   [b][n][d][t]
    float* down_t   = out + 131072;   // 2048
    float* uqp      = out + 133120;   // 131072
    float* dsvp     = out + 264192;   // 131072  (ends 395264 << 4194304)

    k_types<<<Bq * Tq, Hq, 0, stream>>>(types, W_types, b_types, down,
                                        types_h, types_hT, down_t);
    k_ctx<<<Bq * Lq / RPB, 256, 0, stream>>>(context, W_context, b_context, upon, down,
                                             ctx_hT, uqp, dsvp);
    k_attn<<<Bq * Lq, Hq, 0, stream>>>(ctx_hT, types_h, types_hT, cross, uqp, dsvp,
                                       down_t, cmask, update);
    k_out<<<Bq * Lq / RPB, 256, 0, stream>>>(update, context, W_out, b_out, out);
}